// Round 2
// baseline (80.814 us; speedup 1.0000x reference)
//
#include <hip/hip_runtime.h>

#define B_ 4
#define C_ 64
#define N_ 512
#define H_ 128   // hidden width = 2C

typedef float v2f __attribute__((ext_vector_type(2)));
typedef float v4f __attribute__((ext_vector_type(4)));

#define XS_STRIDE 72   // floats; xs is [c][r] (c-major), r 0..63

// ---------------------------------------------------------------------------
// Single fused kernel — no workspace, one launch.
//   Work tile (it,jt,b), 32x32 outputs:
//     phase 1: stage x[b, :, i-rows] and x[b, :, j-rows] into LDS (c-major)
//     phase 2: per-thread proj of 4 i-rows and 4 j-rows x 4 h over c=0..63,
//              W1 read from global (L1/L2-hot, wave-coalesced 512B), b1 folded
//              into R. Results written XOR-swizzled into Lt4/Rt4.
//     phase 3: pair loop (identical to the previous pair_kernel):
//              out[i,j] = (j>i) ? sum_h relu(L[i,h]+R[j,h])*W2[h] + b2 : 0
//   Redundancy: each row-tile's proj is recomputed per work tile (~8.5x), but
//   proj is ~1 MFLOP/block — cheap vs. a second launch + 2 MB ws round-trip.
// Grid: 1024 blocks x 256 threads. Blocks 0..543 = upper-triangle work tiles
// (dispatch first, balance CUs); 544..1023 = strictly-lower zero tiles.
// LDS: 18 + 16 + 16 = 50 KB -> 3 blocks/CU.
// ---------------------------------------------------------------------------
__global__ __launch_bounds__(256) void fused_kernel(
    const float* __restrict__ x, const float* __restrict__ W1,
    const float* __restrict__ b1, const float* __restrict__ W2,
    const float* __restrict__ b2, float* __restrict__ out)
{
    __shared__ float xs[64 * XS_STRIDE];   // 18 KB: xs[c][r], r<32 i-rows, r>=32 j-rows
    __shared__ v4f Lt4[32 * 32];           // 16 KB
    __shared__ v4f Rt4[32 * 32];           // 16 KB

    const int t = threadIdx.x;
    int b, it, jt;
    {
        int bid = blockIdx.x;
        if (bid >= 544) {
            // strictly-lower tile: zero-fill (row it has it tiles, jt in [0,it))
            int z = bid - 544;
            b = z & 3;
            int k = z >> 2;                    // 0..119
            it = 1;
            while (k >= it) { k -= it; ++it; }
            jt = k;
            float* outb = out + b * (N_ * N_);
            const int r = t >> 3, cq = t & 7;  // 32 rows x 8 float4-cols
            *(float4*)(outb + (it * 32 + r) * N_ + jt * 32 + cq * 4) =
                make_float4(0.f, 0.f, 0.f, 0.f);
            return;
        }
        // work tile: row it has 16-it tiles, jt in [it,16)
        b = bid & 3;
        int k = bid >> 2;                      // 0..135
        it = 0;
        while (k >= 16 - it) { k -= 16 - it; ++it; }
        jt = it + k;
    }
    const int ti0 = it * 32, tj0 = jt * 32;
    float* outb = out + b * (N_ * N_);

    // ---- phase 1: stage x tiles, c-major. 1024 float4: idx -> c=idx>>4, q=idx&15
    {
        const float* xb = x + b * (C_ * N_);
        #pragma unroll
        for (int k = 0; k < 4; ++k) {
            int idx = t + k * 256;
            int c = idx >> 4, q = idx & 15;
            int r0 = q * 4;                    // 0..60, quads never straddle r=32
            int gcol = (r0 < 32) ? (ti0 + r0) : (tj0 + (r0 - 32));
            v4f v = *(const v4f*)(xb + c * N_ + gcol);
            *(v4f*)(xs + c * XS_STRIDE + r0) = v;
        }
    }
    __syncthreads();

    // ---- phase 2: proj. thread = (hq = t&31 h-quad, rg = t>>5 row-group of 4)
    {
        const int hq = t & 31;
        const int rg = t >> 5;
        const int r0 = rg * 4;
        const v4f* W14 = (const v4f*)W1;
        v4f bv = *(const v4f*)(b1 + hq * 4);

        v2f La[4][2], Ra[4][2];
        #pragma unroll
        for (int k = 0; k < 4; ++k) {
            La[k][0] = (v2f){0.f, 0.f};
            La[k][1] = (v2f){0.f, 0.f};
            Ra[k][0] = (v2f){bv.x, bv.y};
            Ra[k][1] = (v2f){bv.z, bv.w};
        }

        #pragma unroll 4
        for (int c = 0; c < 64; ++c) {
            v4f wl4 = W14[c * 32 + hq];          // L half of W1
            v4f wr4 = W14[(64 + c) * 32 + hq];   // R half
            v4f xi = *(const v4f*)(xs + c * XS_STRIDE + r0);        // 4 i-rows
            v4f xj = *(const v4f*)(xs + c * XS_STRIDE + 32 + r0);   // 4 j-rows
            v2f wll = wl4.xy, wlh = wl4.zw;
            v2f wrl = wr4.xy, wrh = wr4.zw;
            #pragma unroll
            for (int k = 0; k < 4; ++k) {
                v2f xik = {xi[k], xi[k]};
                v2f xjk = {xj[k], xj[k]};
                La[k][0] = __builtin_elementwise_fma(wll, xik, La[k][0]);
                La[k][1] = __builtin_elementwise_fma(wlh, xik, La[k][1]);
                Ra[k][0] = __builtin_elementwise_fma(wrl, xjk, Ra[k][0]);
                Ra[k][1] = __builtin_elementwise_fma(wrh, xjk, Ra[k][1]);
            }
        }

        // write XOR-swizzled: sc = hq ^ (row>>2), row>>2 == rg for all 4 rows
        const int sc = hq ^ rg;
        #pragma unroll
        for (int k = 0; k < 4; ++k) {
            Lt4[(r0 + k) * 32 + sc] =
                (v4f){La[k][0].x, La[k][0].y, La[k][1].x, La[k][1].y};
            Rt4[(r0 + k) * 32 + sc] =
                (v4f){Ra[k][0].x, Ra[k][0].y, Ra[k][1].x, Ra[k][1].y};
        }
    }
    __syncthreads();

    // ---- phase 3: pair loop (identical to previous pair_kernel)
    const int w    = t >> 6;
    const int lane = t & 63;
    const int til  = (w >> 1) * 16 + (lane >> 3) * 2;  // local i base (2 rows)
    const int tjl  = (w & 1) * 16 + (lane & 7) * 2;    // local j base (2 cols)
    const int rotL = til >> 2;                         // (til+1)>>2 == til>>2 (til even)
    const int rotR = tjl >> 2;

    const v4f* Lp  = Lt4 + til * 32;
    const v4f* Rp  = Rt4 + tjl * 32;
    const v4f* W24 = (const v4f*)W2;

    v2f c00l = {0.f, 0.f}, c00h = {0.f, 0.f};
    v2f c01l = {0.f, 0.f}, c01h = {0.f, 0.f};
    v2f c10l = {0.f, 0.f}, c10h = {0.f, 0.f};
    v2f c11l = {0.f, 0.f}, c11h = {0.f, 0.f};

    #pragma unroll 8
    for (int hc = 0; hc < 32; ++hc) {
        const int oL = hc ^ rotL;
        const int oR = hc ^ rotR;
        v4f L0 = Lp[oL];
        v4f L1 = Lp[32 + oL];                  // same addr reg, offset:512
        v4f R0 = Rp[oR];
        v4f R1 = Rp[32 + oR];
        v4f wv = W24[hc];                      // wave-uniform -> scalar load
        v2f wl = wv.xy, wh = wv.zw;
        const v2f z2 = {0.f, 0.f};
        v2f s;
        s = __builtin_elementwise_max(L0.xy + R0.xy, z2);
        c00l = __builtin_elementwise_fma(s, wl, c00l);
        s = __builtin_elementwise_max(L0.zw + R0.zw, z2);
        c00h = __builtin_elementwise_fma(s, wh, c00h);
        s = __builtin_elementwise_max(L0.xy + R1.xy, z2);
        c01l = __builtin_elementwise_fma(s, wl, c01l);
        s = __builtin_elementwise_max(L0.zw + R1.zw, z2);
        c01h = __builtin_elementwise_fma(s, wh, c01h);
        s = __builtin_elementwise_max(L1.xy + R0.xy, z2);
        c10l = __builtin_elementwise_fma(s, wl, c10l);
        s = __builtin_elementwise_max(L1.zw + R0.zw, z2);
        c10h = __builtin_elementwise_fma(s, wh, c10h);
        s = __builtin_elementwise_max(L1.xy + R1.xy, z2);
        c11l = __builtin_elementwise_fma(s, wl, c11l);
        s = __builtin_elementwise_max(L1.zw + R1.zw, z2);
        c11h = __builtin_elementwise_fma(s, wh, c11h);
    }

    const float bias2 = b2[0];
    float a00 = (c00l.x + c00l.y) + (c00h.x + c00h.y);
    float a01 = (c01l.x + c01l.y) + (c01h.x + c01h.y);
    float a10 = (c10l.x + c10l.y) + (c10h.x + c10h.y);
    float a11 = (c11l.x + c11l.y) + (c11h.x + c11h.y);

    const int gi0 = ti0 + til, gj0 = tj0 + tjl;
    float2 v0, v1;
    v0.x = (gj0     > gi0    ) ? (a00 + bias2) : 0.f;
    v0.y = (gj0 + 1 > gi0    ) ? (a01 + bias2) : 0.f;
    v1.x = (gj0     > gi0 + 1) ? (a10 + bias2) : 0.f;
    v1.y = (gj0 + 1 > gi0 + 1) ? (a11 + bias2) : 0.f;
    *(float2*)(outb + gi0 * N_ + gj0) = v0;
    *(float2*)(outb + (gi0 + 1) * N_ + gj0) = v1;
}

extern "C" void kernel_launch(void* const* d_in, const int* in_sizes, int n_in,
                              void* d_out, int out_size, void* d_ws, size_t ws_size,
                              hipStream_t stream)
{
    const float* x  = (const float*)d_in[0];
    const float* W1 = (const float*)d_in[1];
    const float* b1 = (const float*)d_in[2];
    const float* W2 = (const float*)d_in[3];
    const float* b2 = (const float*)d_in[4];
    float* out = (float*)d_out;
    (void)d_ws; (void)ws_size;   // workspace intentionally untouched

    fused_kernel<<<1024, 256, 0, stream>>>(x, W1, b1, W2, b2, out);
}

// Round 3
// 77.509 us; speedup vs baseline: 1.0426x; 1.0426x over previous
//
#include <hip/hip_runtime.h>

#define B_ 4
#define C_ 64
#define N_ 512
#define H_ 128   // hidden width = 2C

typedef float v2f __attribute__((ext_vector_type(2)));
typedef float v4f __attribute__((ext_vector_type(4)));

// zero-tile count per 32-row band, 64-wide j-tiles: tile (it,jt2) is fully in
// the strict lower triangle iff 64*jt2+63 <= 32*it.
__device__ __forceinline__ int zc_of(int it) {
    return (it < 2) ? 0 : (((32 * it - 63) >> 6) + 1);
}

// ---------------------------------------------------------------------------
// Kernel 1: proj (blocks 0..255) + zero-fill of lower-triangle tiles
// (blocks 256..479 — independent of proj results, so they ride in launch 1).
//   proj: L[b,i,h] = sum_c x[b,c,i] * W1[c,h]
//         R[b,j,h] = sum_c x[b,c,j] * W1[64+c,h] + b1[h]
// ---------------------------------------------------------------------------
__global__ __launch_bounds__(256) void proj_zero_kernel(
    const float* __restrict__ x, const float* __restrict__ W1,
    const float* __restrict__ b1, float* __restrict__ Lbuf,
    float* __restrict__ Rbuf, float* __restrict__ out)
{
    __shared__ float Wl[64 * 128];   // 32 KB: one half of W1
    __shared__ float xs[16 * 68];    // x tile, transposed [ii][c], stride 68

    const int t = threadIdx.x;

    if (blockIdx.x >= 256) {
        // zero tile: 32 i-rows x 64 j-cols entirely below the diagonal
        int z = blockIdx.x - 256;              // 0..223
        int b = z & 3;
        int k = z >> 2;                        // 0..55
        int it = 0, jt2 = 0;
        #pragma unroll 1
        for (; it < 16; ++it) {
            int c = zc_of(it);
            if (k < c) { jt2 = k; break; }
            k -= c;
        }
        float* outb = out + b * (N_ * N_);
        const int r = t >> 3, q = t & 7;       // 32 rows x 8 quad-pairs
        float* p = outb + (it * 32 + r) * N_ + jt2 * 64 + q * 4;
        *(float4*)p        = make_float4(0.f, 0.f, 0.f, 0.f);
        *(float4*)(p + 32) = make_float4(0.f, 0.f, 0.f, 0.f);
        return;
    }

    const int half = blockIdx.x >> 7;          // 0 = L, 1 = R
    const int rem  = blockIdx.x & 127;
    const int b    = rem >> 5;
    const int i0   = (rem & 31) * 16;
    const int cbase = half * 64;

    // stage W half: 2048 float4, coalesced
    const float4* W14 = (const float4*)W1;
    float4* Wl4 = (float4*)Wl;
    #pragma unroll
    for (int k = 0; k < 8; ++k)
        Wl4[t + k * 256] = W14[cbase * 32 + t + k * 256];

    // stage x tile: xs[ii*68 + c] = x[b, c, i0+ii]
    #pragma unroll
    for (int k = 0; k < 4; ++k) {
        int idx = t + k * 256;                  // 0..1023
        int c = idx >> 4, ii = idx & 15;
        xs[ii * 68 + c] = x[b * (C_ * N_) + c * N_ + i0 + ii];
    }
    __syncthreads();

    const int hq  = t & 31;           // column quad (4 h's)
    const int il  = (t >> 5) * 2;     // local row base (2 rows per thread)
    const int col = hq * 4;

    v2f a0l = {0.f, 0.f}, a0h = {0.f, 0.f};
    if (half) {
        float4 bv = *(const float4*)(b1 + col);
        a0l = (v2f){bv.x, bv.y};
        a0h = (v2f){bv.z, bv.w};
    }
    v2f a1l = a0l, a1h = a0h;

    const v4f* Wlv = (const v4f*)Wl;
    #pragma unroll
    for (int c = 0; c < 64; c += 4) {
        float4 xv0 = *(float4*)(xs + il * 68 + c);
        float4 xv1 = *(float4*)(xs + (il + 1) * 68 + c);
        const float* x0p = (const float*)&xv0;
        const float* x1p = (const float*)&xv1;
        #pragma unroll
        for (int cc = 0; cc < 4; ++cc) {
            v4f wv = Wlv[(c + cc) * 32 + hq];
            v2f wl = wv.xy, wh = wv.zw;
            v2f xb0 = {x0p[cc], x0p[cc]};
            v2f xb1 = {x1p[cc], x1p[cc]};
            a0l = __builtin_elementwise_fma(wl, xb0, a0l);
            a0h = __builtin_elementwise_fma(wh, xb0, a0h);
            a1l = __builtin_elementwise_fma(wl, xb1, a1l);
            a1h = __builtin_elementwise_fma(wh, xb1, a1h);
        }
    }

    float* buf = half ? Rbuf : Lbuf;
    float* o = buf + b * (N_ * H_) + (i0 + il) * H_ + col;
    *(float4*)o        = make_float4(a0l.x, a0l.y, a0h.x, a0h.y);
    *(float4*)(o + H_) = make_float4(a1l.x, a1l.y, a1h.x, a1h.y);
}

// ---------------------------------------------------------------------------
// Kernel 2: pairwise scores, 32x64 tiles, 2x4 per-thread blocking.
//   out[b,i,j] = (j > i) ? sum_h relu(L[i,h] + R[j,h]) * W2[h] + b2 : 0
// 288 work blocks (72 upper tiles x 4 b), 256 threads. Per hc per thread:
// 6 ds_read_b128 (2 L + 4 R) for 8 outputs = 0.75 reads/output (was 1.0) —
// pair is LDS-pipe-bound, so this is the lever.
// LDS 48 KB (Lt 32x32 v4f + Rt 64x32 v4f) -> 3 blocks/CU.
// Swizzle sc = hc ^ (row>>2): L reads 2-way broadcast-conflict (free),
// R reads conflict-free (8 distinct rotR per wave).
// ---------------------------------------------------------------------------
__global__ __launch_bounds__(256) void pair_kernel(
    const float* __restrict__ Lbuf, const float* __restrict__ Rbuf,
    const float* __restrict__ W2, const float* __restrict__ b2,
    float* __restrict__ out)
{
    __shared__ v4f Lt4[32 * 32];   // 16 KB
    __shared__ v4f Rt4[64 * 32];   // 32 KB

    const int t = threadIdx.x;
    const int b = blockIdx.x & 3;
    int k = blockIdx.x >> 2;                   // 0..71
    int it = 0, jt2 = 0;
    #pragma unroll 1
    for (; it < 16; ++it) {
        int wc = 8 - zc_of(it);
        if (k < wc) { jt2 = zc_of(it) + k; break; }
        k -= wc;
    }
    const int ti0 = it * 32, tj0 = jt2 * 64;
    float* outb = out + b * (N_ * N_);

    // stage L (1024 v4f) and R (2048 v4f), XOR-swizzled
    const float* Lsrc = Lbuf + b * (N_ * H_) + ti0 * H_;
    const float* Rsrc = Rbuf + b * (N_ * H_) + tj0 * H_;
    #pragma unroll
    for (int kk = 0; kk < 4; ++kk) {
        int idx = t + kk * 256;                // 0..1023
        int row = idx >> 5, hc = idx & 31;
        int sc = hc ^ (row >> 2);
        Lt4[row * 32 + sc] = *(const v4f*)(Lsrc + row * H_ + hc * 4);
    }
    #pragma unroll
    for (int kk = 0; kk < 8; ++kk) {
        int idx = t + kk * 256;                // 0..2047
        int row = idx >> 5, hc = idx & 31;
        int sc = hc ^ (row >> 2);
        Rt4[row * 32 + sc] = *(const v4f*)(Rsrc + row * H_ + hc * 4);
    }
    __syncthreads();

    const int w    = t >> 6;
    const int lane = t & 63;
    const int til  = (w >> 1) * 16 + (lane >> 3) * 2;  // local i base (2 rows)
    const int tjl  = (w & 1) * 32 + (lane & 7) * 4;    // local j base (4 cols)
    const int rotL = til >> 2;                         // const over row pair
    const int rotR = tjl >> 2;                         // const over col quad

    const v4f* Lp  = Lt4 + til * 32;
    const v4f* Rp  = Rt4 + tjl * 32;
    const v4f* W24 = (const v4f*)W2;

    v2f acc[2][4][2];
    #pragma unroll
    for (int r = 0; r < 2; ++r)
        #pragma unroll
        for (int j = 0; j < 4; ++j) {
            acc[r][j][0] = (v2f){0.f, 0.f};
            acc[r][j][1] = (v2f){0.f, 0.f};
        }

    #pragma unroll 4
    for (int hc = 0; hc < 32; ++hc) {
        const int oL = hc ^ rotL;
        const int oR = hc ^ rotR;
        v4f L[2], R[4];
        L[0] = Lp[oL];
        L[1] = Lp[32 + oL];                    // offset:512
        R[0] = Rp[oR];
        R[1] = Rp[32 + oR];
        R[2] = Rp[64 + oR];
        R[3] = Rp[96 + oR];
        v4f wv = W24[hc];                      // wave-uniform -> scalar load
        v2f wl = wv.xy, wh = wv.zw;
        const v2f z2 = {0.f, 0.f};
        #pragma unroll
        for (int r = 0; r < 2; ++r) {
            v2f ll = L[r].xy, lh = L[r].zw;
            #pragma unroll
            for (int j = 0; j < 4; ++j) {
                v2f s;
                s = __builtin_elementwise_max(ll + R[j].xy, z2);
                acc[r][j][0] = __builtin_elementwise_fma(s, wl, acc[r][j][0]);
                s = __builtin_elementwise_max(lh + R[j].zw, z2);
                acc[r][j][1] = __builtin_elementwise_fma(s, wh, acc[r][j][1]);
            }
        }
    }

    const float bias2 = b2[0];
    const int gi0 = ti0 + til, gj0 = tj0 + tjl;
    #pragma unroll
    for (int r = 0; r < 2; ++r) {
        float4 v;
        float a0 = (acc[r][0][0].x + acc[r][0][0].y) + (acc[r][0][1].x + acc[r][0][1].y);
        float a1 = (acc[r][1][0].x + acc[r][1][0].y) + (acc[r][1][1].x + acc[r][1][1].y);
        float a2 = (acc[r][2][0].x + acc[r][2][0].y) + (acc[r][2][1].x + acc[r][2][1].y);
        float a3 = (acc[r][3][0].x + acc[r][3][0].y) + (acc[r][3][1].x + acc[r][3][1].y);
        const int gi = gi0 + r;
        v.x = (gj0     > gi) ? (a0 + bias2) : 0.f;
        v.y = (gj0 + 1 > gi) ? (a1 + bias2) : 0.f;
        v.z = (gj0 + 2 > gi) ? (a2 + bias2) : 0.f;
        v.w = (gj0 + 3 > gi) ? (a3 + bias2) : 0.f;
        *(float4*)(outb + gi * N_ + gj0) = v;
    }
}

extern "C" void kernel_launch(void* const* d_in, const int* in_sizes, int n_in,
                              void* d_out, int out_size, void* d_ws, size_t ws_size,
                              hipStream_t stream)
{
    const float* x  = (const float*)d_in[0];
    const float* W1 = (const float*)d_in[1];
    const float* b1 = (const float*)d_in[2];
    const float* W2 = (const float*)d_in[3];
    const float* b2 = (const float*)d_in[4];
    float* out  = (float*)d_out;
    float* Lbuf = (float*)d_ws;                 // B*N*H floats = 1 MB
    float* Rbuf = Lbuf + B_ * N_ * H_;          // +1 MB

    // launch 1: 256 proj blocks + 224 lower-triangle zero tiles (independent)
    proj_zero_kernel<<<480, 256, 0, stream>>>(x, W1, b1, Lbuf, Rbuf, out);
    // launch 2: 288 work tiles only
    pair_kernel<<<288, 256, 0, stream>>>(Lbuf, Rbuf, W2, b2, out);
}

// Round 4
// 73.985 us; speedup vs baseline: 1.0923x; 1.0476x over previous
//
#include <hip/hip_runtime.h>

#define B_ 4
#define C_ 64
#define N_ 512
#define H_ 128   // hidden width = 2C

typedef float v2f __attribute__((ext_vector_type(2)));
typedef float v4f __attribute__((ext_vector_type(4)));

// ---------------------------------------------------------------------------
// Best measured configuration (75.6 us, round 1). Split structure:
//   proj: 256 blocks, W1-half in LDS, packed-fp32 FMA.
//   pair: 1024 blocks (544 work tiles first, 480 zero tiles trail),
//         32x32 tiles, 2x2 thread blocking, XOR-swizzled LDS, packed fp32.
// Round-2 (fused, ws-free) = +5.2 us: in-kernel proj is VMEM-latency-bound.
// Round-3 (32x64 tiles, 288 blocks) = +1.9 us: occupancy drop beats LDS gain.
// Harness floor: 268 MB poison fill at 82% HBM peak (41 us) + ~25 us resets;
// controllable kernel slice ~8-10 us vs ~5 us compute floor.
// ---------------------------------------------------------------------------
__global__ __launch_bounds__(256) void proj_kernel(
    const float* __restrict__ x, const float* __restrict__ W1,
    const float* __restrict__ b1, float* __restrict__ Lbuf,
    float* __restrict__ Rbuf)
{
    __shared__ float Wl[64 * 128];   // 32 KB: one half of W1 (64 rows x 128 cols)
    __shared__ float xs[16 * 68];    // x tile, transposed [ii][c], padded stride 68

    const int t    = threadIdx.x;
    const int half = blockIdx.x >> 7;          // 0 = L, 1 = R
    const int rem  = blockIdx.x & 127;
    const int b    = rem >> 5;
    const int i0   = (rem & 31) * 16;
    const int cbase = half * 64;

    // stage W half: rows cbase..cbase+63, all 128 cols = 2048 float4, coalesced
    const float4* W14 = (const float4*)W1;
    float4* Wl4 = (float4*)Wl;
    #pragma unroll
    for (int k = 0; k < 8; ++k)
        Wl4[t + k * 256] = W14[cbase * 32 + t + k * 256];

    // stage x tile: xs[ii*68 + c] = x[b, c, i0+ii]
    #pragma unroll
    for (int k = 0; k < 4; ++k) {
        int idx = t + k * 256;                  // 0..1023
        int c = idx >> 4, ii = idx & 15;
        xs[ii * 68 + c] = x[b * (C_ * N_) + c * N_ + i0 + ii];
    }
    __syncthreads();

    const int hq  = t & 31;           // column quad (4 h's)
    const int il  = (t >> 5) * 2;     // local row base (2 rows per thread)
    const int col = hq * 4;

    v2f a0l = {0.f, 0.f}, a0h = {0.f, 0.f};
    if (half) {
        float4 bv = *(const float4*)(b1 + col);
        a0l = (v2f){bv.x, bv.y};
        a0h = (v2f){bv.z, bv.w};
    }
    v2f a1l = a0l, a1h = a0h;

    const v4f* Wlv = (const v4f*)Wl;
    #pragma unroll
    for (int c = 0; c < 64; c += 4) {
        float4 xv0 = *(float4*)(xs + il * 68 + c);
        float4 xv1 = *(float4*)(xs + (il + 1) * 68 + c);
        const float* x0p = (const float*)&xv0;
        const float* x1p = (const float*)&xv1;
        #pragma unroll
        for (int cc = 0; cc < 4; ++cc) {
            v4f wv = Wlv[(c + cc) * 32 + hq];
            v2f wl = wv.xy, wh = wv.zw;
            v2f xb0 = {x0p[cc], x0p[cc]};
            v2f xb1 = {x1p[cc], x1p[cc]};
            a0l = __builtin_elementwise_fma(wl, xb0, a0l);
            a0h = __builtin_elementwise_fma(wh, xb0, a0h);
            a1l = __builtin_elementwise_fma(wl, xb1, a1l);
            a1h = __builtin_elementwise_fma(wh, xb1, a1h);
        }
    }

    float* buf = half ? Rbuf : Lbuf;
    float* o = buf + b * (N_ * H_) + (i0 + il) * H_ + col;
    *(float4*)o        = make_float4(a0l.x, a0l.y, a0h.x, a0h.y);
    *(float4*)(o + H_) = make_float4(a1l.x, a1l.y, a1h.x, a1h.y);
}

__global__ __launch_bounds__(256) void pair_kernel(
    const float* __restrict__ Lbuf, const float* __restrict__ Rbuf,
    const float* __restrict__ W2, const float* __restrict__ b2,
    float* __restrict__ out)
{
    __shared__ v4f Lt4[32 * 32];   // 16 KB
    __shared__ v4f Rt4[32 * 32];   // 16 KB

    const int t = threadIdx.x;
    int b, it, jt;
    {
        int bid = blockIdx.x;
        if (bid >= 544) {
            // strictly-lower tile: zero-fill (row it has it tiles, jt in [0,it))
            int z = bid - 544;
            b = z & 3;
            int k = z >> 2;                    // 0..119
            it = 1;
            while (k >= it) { k -= it; ++it; }
            jt = k;
            float* outb = out + b * (N_ * N_);
            const int r = t >> 3, cq = t & 7;  // 32 rows x 8 float4-cols
            *(float4*)(outb + (it * 32 + r) * N_ + jt * 32 + cq * 4) =
                make_float4(0.f, 0.f, 0.f, 0.f);
            return;
        }
        // work tile: row it has 16-it tiles, jt in [it,16)
        b = bid & 3;
        int k = bid >> 2;                      // 0..135
        it = 0;
        while (k >= 16 - it) { k -= 16 - it; ++it; }
        jt = it + k;
    }
    const int ti0 = it * 32, tj0 = jt * 32;
    float* outb = out + b * (N_ * N_);

    // stage L and R tiles: 1024 v4f each, 4 per thread per tile, XOR-swizzled
    const float* Lsrc = Lbuf + b * (N_ * H_) + ti0 * H_;
    const float* Rsrc = Rbuf + b * (N_ * H_) + tj0 * H_;
    #pragma unroll
    for (int kk = 0; kk < 4; ++kk) {
        int idx = t + kk * 256;                // 0..1023
        int row = idx >> 5, hc = idx & 31;
        int sc = hc ^ (row >> 2);
        Lt4[row * 32 + sc] = *(const v4f*)(Lsrc + row * H_ + hc * 4);
        Rt4[row * 32 + sc] = *(const v4f*)(Rsrc + row * H_ + hc * 4);
    }
    __syncthreads();

    const int w    = t >> 6;
    const int lane = t & 63;
    const int til  = (w >> 1) * 16 + (lane >> 3) * 2;  // local i base (2 rows)
    const int tjl  = (w & 1) * 16 + (lane & 7) * 2;    // local j base (2 cols)
    const int rotL = til >> 2;                         // (til+1)>>2 == til>>2 (til even)
    const int rotR = tjl >> 2;

    const v4f* Lp  = Lt4 + til * 32;
    const v4f* Rp  = Rt4 + tjl * 32;
    const v4f* W24 = (const v4f*)W2;

    v2f c00l = {0.f, 0.f}, c00h = {0.f, 0.f};
    v2f c01l = {0.f, 0.f}, c01h = {0.f, 0.f};
    v2f c10l = {0.f, 0.f}, c10h = {0.f, 0.f};
    v2f c11l = {0.f, 0.f}, c11h = {0.f, 0.f};

    #pragma unroll 8
    for (int hc = 0; hc < 32; ++hc) {
        const int oL = hc ^ rotL;
        const int oR = hc ^ rotR;
        v4f L0 = Lp[oL];
        v4f L1 = Lp[32 + oL];                  // same addr reg, offset:512
        v4f R0 = Rp[oR];
        v4f R1 = Rp[32 + oR];
        v4f wv = W24[hc];                      // wave-uniform -> scalar load
        v2f wl = wv.xy, wh = wv.zw;
        const v2f z2 = {0.f, 0.f};
        v2f s;
        s = __builtin_elementwise_max(L0.xy + R0.xy, z2);
        c00l = __builtin_elementwise_fma(s, wl, c00l);
        s = __builtin_elementwise_max(L0.zw + R0.zw, z2);
        c00h = __builtin_elementwise_fma(s, wh, c00h);
        s = __builtin_elementwise_max(L0.xy + R1.xy, z2);
        c01l = __builtin_elementwise_fma(s, wl, c01l);
        s = __builtin_elementwise_max(L0.zw + R1.zw, z2);
        c01h = __builtin_elementwise_fma(s, wh, c01h);
        s = __builtin_elementwise_max(L1.xy + R0.xy, z2);
        c10l = __builtin_elementwise_fma(s, wl, c10l);
        s = __builtin_elementwise_max(L1.zw + R0.zw, z2);
        c10h = __builtin_elementwise_fma(s, wh, c10h);
        s = __builtin_elementwise_max(L1.xy + R1.xy, z2);
        c11l = __builtin_elementwise_fma(s, wl, c11l);
        s = __builtin_elementwise_max(L1.zw + R1.zw, z2);
        c11h = __builtin_elementwise_fma(s, wh, c11h);
    }

    const float bias2 = b2[0];
    float a00 = (c00l.x + c00l.y) + (c00h.x + c00h.y);
    float a01 = (c01l.x + c01l.y) + (c01h.x + c01h.y);
    float a10 = (c10l.x + c10l.y) + (c10h.x + c10h.y);
    float a11 = (c11l.x + c11l.y) + (c11h.x + c11h.y);

    const int gi0 = ti0 + til, gj0 = tj0 + tjl;
    float2 v0, v1;
    v0.x = (gj0     > gi0    ) ? (a00 + bias2) : 0.f;
    v0.y = (gj0 + 1 > gi0    ) ? (a01 + bias2) : 0.f;
    v1.x = (gj0     > gi0 + 1) ? (a10 + bias2) : 0.f;
    v1.y = (gj0 + 1 > gi0 + 1) ? (a11 + bias2) : 0.f;
    *(float2*)(outb + gi0 * N_ + gj0) = v0;
    *(float2*)(outb + (gi0 + 1) * N_ + gj0) = v1;
}

extern "C" void kernel_launch(void* const* d_in, const int* in_sizes, int n_in,
                              void* d_out, int out_size, void* d_ws, size_t ws_size,
                              hipStream_t stream)
{
    const float* x  = (const float*)d_in[0];
    const float* W1 = (const float*)d_in[1];
    const float* b1 = (const float*)d_in[2];
    const float* W2 = (const float*)d_in[3];
    const float* b2 = (const float*)d_in[4];
    float* out  = (float*)d_out;
    float* Lbuf = (float*)d_ws;                 // B*N*H floats = 1 MB
    float* Rbuf = Lbuf + B_ * N_ * H_;          // +1 MB

    proj_kernel<<<256, 256, 0, stream>>>(x, W1, b1, Lbuf, Rbuf);
    pair_kernel<<<B_ * 256, 256, 0, stream>>>(Lbuf, Rbuf, W2, b2, out);
}